// Round 5
// baseline (2734.084 us; speedup 1.0000x reference)
//
#include <hip/hip_runtime.h>

typedef _Float16 f16;
typedef _Float16 h2_t __attribute__((ext_vector_type(2)));
typedef _Float16 h8_t __attribute__((ext_vector_type(8)));
typedef float    f4_t __attribute__((ext_vector_type(4)));

__device__ __forceinline__ float fdot2u(unsigned int a, unsigned int b, float c) {
  return __builtin_amdgcn_fdot2(__builtin_bit_cast(h2_t, a),
                                __builtin_bit_cast(h2_t, b), c, false);
}

// ============ generic f16-input MFMA GEMM: C[z] = A[z] @ B (+bias)(+accum)(+relu) ============
// C/D layout: col = lane&15, row = (lane>>4)*4 + reg   [m89-verified]
template<int F16OUT, int ACCUM, int RELU, int BIASF>
__global__ __launch_bounds__(256) void gemm16(
    const f16* __restrict__ Ap, long lda, long sAz,
    const f16* __restrict__ Bp, long ldb,
    void* __restrict__ Cp, long ldc, long sCz,
    const float* __restrict__ biasN,
    int M, int N, int K)
{
  const int lane = threadIdx.x & 63;
  const int wv   = threadIdx.x >> 6;
  const int rl = lane & 15, kb = lane >> 4;
  const long z = blockIdx.z;
  const f16* Az = Ap + z * sAz;
  const int rowA = blockIdx.x * 64 + wv * 16 + rl;
  const long rA = (rowA < M) ? rowA : 0;
  const int colBase = blockIdx.y * 64;
  f4_t acc[4];
  #pragma unroll
  for (int c = 0; c < 4; ++c) acc[c] = 0.0f;

  for (int k0 = 0; k0 < K; k0 += 32) {
    h8_t af = *(const h8_t*)(Az + rA * lda + (k0 + kb * 8));
    h8_t bf[4];
    #pragma unroll
    for (int i = 0; i < 8; ++i) {
      long krow = (long)(k0 + kb * 8 + i) * ldb + colBase + rl;
      #pragma unroll
      for (int c = 0; c < 4; ++c) bf[c][i] = Bp[krow + 16 * c];
    }
    #pragma unroll
    for (int c = 0; c < 4; ++c)
      acc[c] = __builtin_amdgcn_mfma_f32_16x16x32_f16(af, bf[c], acc[c], 0, 0, 0);
  }

  #pragma unroll
  for (int c = 0; c < 4; ++c) {
    const int col = colBase + c * 16 + rl;
    #pragma unroll
    for (int g = 0; g < 4; ++g) {
      const int row = blockIdx.x * 64 + wv * 16 + kb * 4 + g;
      if (row < M) {
        float v = acc[c][g];
        const long ci = z * sCz + (long)row * ldc + col;
        if (BIASF) v += biasN[col];
        if (ACCUM) v += F16OUT ? (float)((const f16*)Cp)[ci] : ((const float*)Cp)[ci];
        if (RELU) v = fmaxf(v, 0.0f);
        if (F16OUT) ((f16*)Cp)[ci] = (f16)v;
        else        ((float*)Cp)[ci] = v;
      }
    }
  }
}

// ============ small helper kernels ============
// merged f32->f16 conversion of E, Fw, B1w (262144 each) + B2w (32768)
__global__ void k_cvt4(const float* __restrict__ a, f16* __restrict__ da,
                       const float* __restrict__ b, f16* __restrict__ db,
                       const float* __restrict__ c, f16* __restrict__ dc,
                       const float* __restrict__ d, f16* __restrict__ dd) {
  int i = blockIdx.x * 256 + threadIdx.x;   // 819200 total
  if (i < 262144) da[i] = (f16)a[i];
  else if (i < 524288) db[i - 262144] = (f16)b[i - 262144];
  else if (i < 786432) dc[i - 524288] = (f16)c[i - 524288];
  else if (i < 819200) dd[i - 786432] = (f16)d[i - 786432];
}

__global__ void k_build_cv(const float* __restrict__ C2, const float* __restrict__ mul,
                           f16* __restrict__ cv) {
  int i = blockIdx.x * 256 + threadIdx.x;   // 512*512
  int r = i >> 9;
  cv[i] = (f16)(C2[i] / mul[r]);
}

// DvT (64x512): DvT[k][n] = Dtild[n][k]/mul[n]
__global__ void k_build_dvt(const float* __restrict__ Dt, const float* __restrict__ mul,
                            f16* __restrict__ dvt) {
  int i = blockIdx.x * 256 + threadIdx.x;   // 64*512
  int k = i >> 9, n = i & 511;
  dvt[i] = (f16)(Dt[n * 64 + k] / mul[n]);
}

__global__ void k_2im(const float* __restrict__ s, f16* __restrict__ d) {
  int i = blockIdx.x * 256 + threadIdx.x;
  int r = i >> 9, c = i & 511;
  d[i] = (f16)(((r == c) ? 2.0f : 0.0f) - s[i]);
}

__global__ void k_tr16(const f16* __restrict__ s, f16* __restrict__ d, int R, int C) {
  int i = blockIdx.x * 256 + threadIdx.x;
  if (i < R * C) { int j = i / R, r = i % R; d[i] = s[r * C + j]; }
}

__global__ void k_woutt(const float* __restrict__ C1, const float* __restrict__ D11,
                        const float* __restrict__ D12, f16* __restrict__ Wo) {
  int i = blockIdx.x * 256 + threadIdx.x;   // 1088*64
  int k = i >> 6, j = i & 63;
  float v = (k < 512) ? C1[j * 512 + k]
          : (k < 1024) ? D11[j * 512 + (k - 512)]
                       : D12[j * 64 + (k - 1024)];
  Wo[i] = (f16)v;
}

__global__ void k_cb(const f16* __restrict__ X, const float* __restrict__ Fb,
                     float* __restrict__ cb) {
  int i = threadIdx.x;
  float a = 0.0f;
  for (int k = 0; k < 512; ++k) a += (float)X[i * 512 + k] * Fb[k];
  cb[i] = a;
}

__global__ void k_bias0(const f16* __restrict__ Cv, const float* __restrict__ cb,
                        const float* __restrict__ bv, float* __restrict__ b0) {
  int i = blockIdx.x * 512 + threadIdx.x;
  if (i < 512) b0[i] = cb[i];
  else {
    int j = i - 512;
    float a = bv[j];
    for (int k = 0; k < 512; ++k) a += (float)Cv[j * 512 + k] * cb[k];
    b0[i] = a;
  }
}

// u (B,NU,T) f32 -> UP2 [b][1025][64] f16 (row 1024 per batch = zero pad)
__global__ void k_packu(const float* __restrict__ u, f16* __restrict__ up) {
  __shared__ f16 tile[64][65];
  int b = blockIdx.y, t0 = blockIdx.x << 6;
  int tid = threadIdx.x;
  #pragma unroll
  for (int it = 0; it < 16; ++it) {
    int idx = it * 256 + tid; int i = idx >> 6, tt = idx & 63;
    tile[tt][i] = (f16)u[((long)b * 64 + i) * 1024 + t0 + tt];
  }
  __syncthreads();
  #pragma unroll
  for (int it = 0; it < 16; ++it) {
    int idx = it * 256 + tid; int tt = idx >> 6, i = idx & 63;
    up[((long)b * 1025 + t0 + tt) * 64 + i] = tile[tt][i];
  }
}

// Pack Wbig = [[A1 A2],[M1 M2]] (1024x1024 f16) into per-thread register layout.
__global__ void k_packw(const f16* __restrict__ A1, const f16* __restrict__ A2,
                        const f16* __restrict__ M1, const f16* __restrict__ M2,
                        unsigned int* __restrict__ Wp) {
  int U = blockIdx.x * 256 + threadIdx.x;   // 524288
  int p = U & 3; int V = U >> 2;
  int tid = V & 511; int sj = V >> 9;
  int jj = sj & 31; int s = sj >> 5;
  int q = tid & 3, r = tid >> 2;
  int R = s * 128 + r;
  int k = q * 256 + jj * 8 + p * 2;
  f16 g0, g1;
  if (R < 512) {
    if (k < 512) { g0 = A1[R * 512 + k];         g1 = A1[R * 512 + k + 1]; }
    else         { g0 = A2[R * 512 + k - 512];   g1 = A2[R * 512 + k - 511]; }
  } else {
    int Rm = R - 512;
    if (k < 512) { g0 = M1[Rm * 512 + k];        g1 = M1[Rm * 512 + k + 1]; }
    else         { g0 = M2[Rm * 512 + k - 512];  g1 = M2[Rm * 512 + k - 511]; }
  }
  unsigned int lo = __builtin_bit_cast(unsigned short, g0);
  unsigned int hi = __builtin_bit_cast(unsigned short, g1);
  Wp[U] = lo | (hi << 16);
}

// w0 (32x512 f16) -> ring slot 0 w-half, tagged with t=0
__global__ void k_tag0(const f16* __restrict__ W0, unsigned int* __restrict__ ring) {
  int i = blockIdx.x * 256 + threadIdx.x;   // 16384
  int b = i >> 9, j = i & 511;
  unsigned int bits = (unsigned int)__builtin_bit_cast(unsigned short, W0[i]);
  ring[(long)b * 1024 + 512 + j] = bits << 16;   // (val<<16)|tag, tag=0
}

// ============ the sequential scan: persistent, 256 WGs = 32 batches x 8 slices ============
// Sync: self-validating tagged dwords, NO flags, NO fences, NO store drains on the
// critical path. ring[t&3][b][j] = (f16val<<16)|t. Producer's data store IS the signal.
// Consumer threads spin on their own 2 dwords (tag==t-1) -> assemble -> LDS (double-
// buffered by t&1 => single barrier per step). Ring WAR safety: writer of step t+2
// requires all threads consumed step t (lockstep chain) => depth 4 has 2 steps slack.
__global__ __launch_bounds__(512, 1) void k_scan(
    const uint4* __restrict__ Wp4,
    const f16* __restrict__ bHV,
    const float* __restrict__ b0,
    unsigned int* __restrict__ ring,   // [4][32][1024] tagged dwords
    unsigned int* __restrict__ hist)   // [1024][32][512] packed f16 pairs
{
  const int wg = blockIdx.x;
  const int s = wg >> 5, b = wg & 31;
  const int tid = threadIdx.x;
  const int q = tid & 3, r = tid >> 2;     // 4-way K-split, 128 rows/slice
  const int R = (s << 7) + r;
  __shared__ __align__(16) unsigned int lds[2 * 528];   // double-buffered, 132-padded chunks

  // weights: 128 dwords/thread, register-resident; asm keep-alive pins them (round-3
  // lesson: without it the compiler sinks the loads into the t-loop => re-reads 256KB/step)
  uint4 wreg[32];
  #pragma unroll
  for (int j = 0; j < 32; ++j) wreg[j] = Wp4[(long)(s * 32 + j) * 512 + tid];
  #pragma unroll
  for (int j = 0; j < 32; ++j)
    asm volatile("" : "+v"(wreg[j].x), "+v"(wreg[j].y), "+v"(wreg[j].z), "+v"(wreg[j].w));

  const float b0r = b0[R];
  const bool isV = (s >= 4);

  for (int t = 1; t < 1024; ++t) {
    // bias prefetch (independent; overlaps the spin)
    float bsv = (float)bHV[((long)b * 1025 + (t - 1)) * 1024 + R];

    // consume step t-1: per-thread spin on own 2 tagged dwords
    const unsigned int* rp = ring + (((t - 1) & 3) * 32 + b) * 1024 + tid * 2;
    const unsigned int tg = (unsigned int)(t - 1);
    unsigned int d0, d1;
    for (;;) {
      d0 = __hip_atomic_load(rp,     __ATOMIC_RELAXED, __HIP_MEMORY_SCOPE_AGENT);
      d1 = __hip_atomic_load(rp + 1, __ATOMIC_RELAXED, __HIP_MEMORY_SCOPE_AGENT);
      if ((((d0 ^ tg) | (d1 ^ tg)) & 0xFFFFu) == 0u) break;
    }
    asm volatile("" ::: "memory");
    unsigned int pk = (d0 >> 16) | (d1 & 0xFFFF0000u);   // packed f16 pair (2tid, 2tid+1)
    lds[(t & 1) * 528 + (tid >> 7) * 132 + (tid & 127)] = pk;
    __syncthreads();   // only barrier per step; prev-iter stores drained here (w/ slack)

    const unsigned int* lp = lds + (t & 1) * 528 + q * 132;
    float acc = 0.0f;
    #pragma unroll
    for (int jj = 0; jj < 32; ++jj) {
      uint4 s4 = *(const uint4*)(lp + jj * 4);
      acc = fdot2u(s4.x, wreg[jj].x, acc);
      acc = fdot2u(s4.y, wreg[jj].y, acc);
      acc = fdot2u(s4.z, wreg[jj].z, acc);
      acc = fdot2u(s4.w, wreg[jj].w, acc);
    }
    acc += __shfl_xor(acc, 1, 64);
    acc += __shfl_xor(acc, 2, 64);

    float val = acc + bsv + b0r;
    if (isV) val = fmaxf(val, 0.0f);
    f16 hv = (f16)val;
    unsigned int hb = (unsigned int)__builtin_bit_cast(unsigned short, hv);

    // history for step t-1 (off critical path; drains at next iter's barrier)
    if (s == 0)
      hist[((long)(t - 1) * 32 + b) * 512 + tid] = pk;

    if (t == 1023) {   // final row: never consumed via ring; producers store history directly
      unsigned int nb = __shfl_down(hb, 4, 64);
      if ((tid & 7) == 0)
        hist[((long)1023 * 32 + b) * 512 + (R >> 1)] = hb | (nb << 16);
    } else {
      if (q == 0)
        __hip_atomic_store(ring + ((t & 3) * 32 + b) * 1024 + R,
                           (hb << 16) | (unsigned int)t,
                           __ATOMIC_RELAXED, __HIP_MEMORY_SCOPE_AGENT);
    }
  }
}

// C32 [b][t][j] f32 -> out [b][j][t]
__global__ void k_trout(const float* __restrict__ C, float* __restrict__ out) {
  __shared__ float tile[64][65];
  int b = blockIdx.y, t0 = blockIdx.x << 6;
  int tid = threadIdx.x;
  #pragma unroll
  for (int it = 0; it < 16; ++it) {
    int idx = it * 256 + tid; int tt = idx >> 6, j = idx & 63;
    tile[j][tt] = C[((long)b * 1024 + t0 + tt) * 64 + j];
  }
  __syncthreads();
  #pragma unroll
  for (int it = 0; it < 16; ++it) {
    int idx = it * 256 + tid; int j = idx >> 6, tt = idx & 63;
    out[((long)b * 64 + j) * 1024 + t0 + tt] = tile[j][tt];
  }
}

// ============ host ============
extern "C" void kernel_launch(void* const* d_in, const int* in_sizes, int n_in,
                              void* d_out, int out_size, void* d_ws, size_t ws_size,
                              hipStream_t stream) {
  (void)in_sizes; (void)n_in; (void)out_size; (void)ws_size;
  const float* u   = (const float*)d_in[0];
  const float* E   = (const float*)d_in[1];
  const float* Fw  = (const float*)d_in[2];
  const float* Fb  = (const float*)d_in[3];
  const float* B1w = (const float*)d_in[4];
  const float* B2w = (const float*)d_in[5];
  const float* C2t = (const float*)d_in[6];
  const float* bv  = (const float*)d_in[7];
  const float* Dt  = (const float*)d_in[8];
  const float* C1w = (const float*)d_in[9];
  const float* D11 = (const float*)d_in[10];
  const float* D12 = (const float*)d_in[11];
  const float* by  = (const float*)d_in[12];
  const float* mul = (const float*)d_in[13];
  float* out = (float*)d_out;

  char* w = (char*)d_ws;
  size_t off = 0;
  auto alloc = [&](size_t bytes) { size_t o = off; off += (bytes + 255) & ~(size_t)255; return o; };

  f16*  UP2   = (f16*)(w + alloc(32L * 1025 * 64 * 2));  // u packed [b][1025][64], last row 0
  f16*  E16   = (f16*)(w + alloc(262144L * 2));
  f16*  F16   = (f16*)(w + alloc(262144L * 2));
  f16*  B116  = (f16*)(w + alloc(262144L * 2));
  f16*  B216  = (f16*)(w + alloc(32768L * 2));
  f16*  CV16  = (f16*)(w + alloc(262144L * 2));
  f16*  CATB  = (f16*)(w + alloc(65536L * 2));           // [CvA3T (64x512); DvT (64x512)]
  f16*  CVA3T = CATB;
  f16*  DVT   = CATB + 32768;
  f16*  XA    = (f16*)(w + alloc(262144L * 2));
  f16*  XB    = (f16*)(w + alloc(262144L * 2));
  f16*  Z16   = (f16*)(w + alloc(262144L * 2));
  float* Y32  = (float*)(w + alloc(262144L * 4));
  f16*  A1    = (f16*)(w + alloc(262144L * 2));
  f16*  A2    = (f16*)(w + alloc(262144L * 2));
  f16*  A3    = (f16*)(w + alloc(32768L * 2));
  f16*  M1    = (f16*)(w + alloc(262144L * 2));
  f16*  M2    = (f16*)(w + alloc(262144L * 2));
  f16*  CVA3  = (f16*)(w + alloc(32768L * 2));
  f16*  A3T   = (f16*)(w + alloc(32768L * 2));
  unsigned int* WPK = (unsigned int*)(w + alloc(524288L * 4));
  f16*  WOUT  = (f16*)(w + alloc(69632L * 2));           // 1088x64
  float* CB   = (float*)(w + alloc(512L * 4));
  float* B0   = (float*)(w + alloc(1024L * 4));
  f16*  W0    = (f16*)(w + alloc(16384L * 2));           // w0 (32x512)
  unsigned int* RING = (unsigned int*)(w + alloc(4L * 32 * 1024 * 4));   // tagged state ring
  f16*  BHV   = (f16*)(w + alloc(32L * 1025 * 1024 * 2));  // per-step biases [b][1025][1024]
  unsigned int* HIST = (unsigned int*)(w + alloc(1024L * 32 * 512 * 4)); // state history [t][b][512] dword-pairs
  float* C32  = (float*)(w + alloc(2097152L * 4));         // y pre-transpose [b][t][64]

  // init (ws re-poisoned to 0xAA before every timed launch; tag 0xAAAA never matches t<1024)
  (void)hipMemsetAsync(UP2, 0, 32L * 1025 * 64 * 2, stream);     // zero pad rows
  (void)hipMemsetAsync(RING, 0, 32L * 1024 * 4, stream);         // slot 0: h0=0, tag 0

  k_packu<<<dim3(16, 32), 256, 0, stream>>>(u, UP2);
  k_cvt4<<<3200, 256, 0, stream>>>(E, E16, Fw, F16, B1w, B116, B2w, B216);
  k_build_cv<<<1024, 256, 0, stream>>>(C2t, mul, CV16);
  k_build_dvt<<<128, 256, 0, stream>>>(Dt, mul, DVT);

  // Newton: X <- X(2I - E X), X0 = 2I - E (3 iters: residual ~2.6e-6 << f16 floor)
  k_2im<<<1024, 256, 0, stream>>>(E, XA);
  f16 *X = XA, *Xo = XB;
  for (int it = 0; it < 3; ++it) {
    gemm16<0,0,0,0><<<dim3(8,8,1), 256, 0, stream>>>(E16, 512, 0, X, 512, Y32, 512, 0, nullptr, 512, 512, 512);
    k_2im<<<1024, 256, 0, stream>>>(Y32, Z16);
    gemm16<1,0,0,0><<<dim3(8,8,1), 256, 0, stream>>>(X, 512, 0, Z16, 512, Xo, 512, 0, nullptr, 512, 512, 512);
    f16* tmp = X; X = Xo; Xo = tmp;
  }

  // fused weights
  gemm16<1,0,0,0><<<dim3(8,8,1), 256, 0, stream>>>(X, 512, 0, F16, 512, A1, 512, 0, nullptr, 512, 512, 512);
  gemm16<1,0,0,0><<<dim3(8,8,1), 256, 0, stream>>>(X, 512, 0, B116, 512, A2, 512, 0, nullptr, 512, 512, 512);
  gemm16<1,0,0,0><<<dim3(8,1,1), 256, 0, stream>>>(X, 512, 0, B216, 64, A3, 64, 0, nullptr, 512, 64, 512);
  gemm16<1,0,0,0><<<dim3(8,8,1), 256, 0, stream>>>(CV16, 512, 0, A1, 512, M1, 512, 0, nullptr, 512, 512, 512);
  gemm16<1,0,0,0><<<dim3(8,8,1), 256, 0, stream>>>(CV16, 512, 0, A2, 512, M2, 512, 0, nullptr, 512, 512, 512);
  gemm16<1,0,0,0><<<dim3(8,1,1), 256, 0, stream>>>(CV16, 512, 0, A3, 64, CVA3, 64, 0, nullptr, 512, 64, 512);
  k_tr16<<<128, 256, 0, stream>>>(A3, A3T, 512, 64);
  k_tr16<<<128, 256, 0, stream>>>(CVA3, CVA3T, 512, 64);
  k_woutt<<<272, 256, 0, stream>>>(C1w, D11, D12, WOUT);
  k_cb<<<1, 512, 0, stream>>>(X, Fb, CB);
  k_bias0<<<2, 512, 0, stream>>>(CV16, CB, bv, B0);
  k_packw<<<2048, 256, 0, stream>>>(A1, A2, M1, M2, WPK);

  // per-step input biases into BHV [b][1025][1024]:
  //   biasH[t] = u_t @ A3T ; biasV[t] = [u_t ; u_{t+1}] @ [CvA3T ; DvT] (K=128, fused)
  gemm16<1,0,0,0><<<dim3(513,8,1), 256, 0, stream>>>(UP2, 64, 0, A3T, 512, BHV, 1024, 0, nullptr, 32800, 512, 64);
  gemm16<1,0,0,0><<<dim3(513,8,1), 256, 0, stream>>>(UP2, 64, 0, CVA3T, 512, BHV + 512, 1024, 0, nullptr, 32800, 512, 128);
  // w0 = relu(u_0 @ DvT + bv) -> W0, then tag into ring slot 0
  gemm16<1,0,1,1><<<dim3(1,8,32), 256, 0, stream>>>(UP2, 64, 65600, DVT, 512, W0, 512, 512, bv, 1, 512, 64);
  k_tag0<<<64, 256, 0, stream>>>(W0, RING);

  // the sequential recurrence
  k_scan<<<256, 512, 0, stream>>>((const uint4*)WPK, BHV, B0, RING, HIST);

  // y = [h;w] @ WoutT[0:1024] + u @ WoutT[1024:1088] + by   (batched over b)
  gemm16<0,0,0,0><<<dim3(16,1,32), 256, 0, stream>>>((const f16*)HIST, 32768, 1024, WOUT, 64, C32, 64, 65536, nullptr, 1024, 64, 1024);
  gemm16<0,1,0,1><<<dim3(16,1,32), 256, 0, stream>>>(UP2, 64, 65600, WOUT + 65536, 64, C32, 64, 65536, by, 1024, 64, 64);
  k_trout<<<dim3(16, 32), 256, 0, stream>>>(C32, out);
}

// Round 7
// 2515.100 us; speedup vs baseline: 1.0871x; 1.0871x over previous
//
#include <hip/hip_runtime.h>

typedef _Float16 f16;
typedef _Float16 h2_t __attribute__((ext_vector_type(2)));
typedef _Float16 h8_t __attribute__((ext_vector_type(8)));
typedef float    f4_t __attribute__((ext_vector_type(4)));

__device__ __forceinline__ float fdot2u(unsigned int a, unsigned int b, float c) {
  return __builtin_amdgcn_fdot2(__builtin_bit_cast(h2_t, a),
                                __builtin_bit_cast(h2_t, b), c, false);
}

// ============ generic f16-input MFMA GEMM: C[z] = A[z] @ B (+bias)(+accum)(+relu) ============
// C/D layout: col = lane&15, row = (lane>>4)*4 + reg   [m89-verified]
template<int F16OUT, int ACCUM, int RELU, int BIASF>
__global__ __launch_bounds__(256) void gemm16(
    const f16* __restrict__ Ap, long lda, long sAz,
    const f16* __restrict__ Bp, long ldb,
    void* __restrict__ Cp, long ldc, long sCz,
    const float* __restrict__ biasN,
    int M, int N, int K)
{
  const int lane = threadIdx.x & 63;
  const int wv   = threadIdx.x >> 6;
  const int rl = lane & 15, kb = lane >> 4;
  const long z = blockIdx.z;
  const f16* Az = Ap + z * sAz;
  const int rowA = blockIdx.x * 64 + wv * 16 + rl;
  const long rA = (rowA < M) ? rowA : 0;
  const int colBase = blockIdx.y * 64;
  f4_t acc[4];
  #pragma unroll
  for (int c = 0; c < 4; ++c) acc[c] = 0.0f;

  for (int k0 = 0; k0 < K; k0 += 32) {
    h8_t af = *(const h8_t*)(Az + rA * lda + (k0 + kb * 8));
    h8_t bf[4];
    #pragma unroll
    for (int i = 0; i < 8; ++i) {
      long krow = (long)(k0 + kb * 8 + i) * ldb + colBase + rl;
      #pragma unroll
      for (int c = 0; c < 4; ++c) bf[c][i] = Bp[krow + 16 * c];
    }
    #pragma unroll
    for (int c = 0; c < 4; ++c)
      acc[c] = __builtin_amdgcn_mfma_f32_16x16x32_f16(af, bf[c], acc[c], 0, 0, 0);
  }

  #pragma unroll
  for (int c = 0; c < 4; ++c) {
    const int col = colBase + c * 16 + rl;
    #pragma unroll
    for (int g = 0; g < 4; ++g) {
      const int row = blockIdx.x * 64 + wv * 16 + kb * 4 + g;
      if (row < M) {
        float v = acc[c][g];
        const long ci = z * sCz + (long)row * ldc + col;
        if (BIASF) v += biasN[col];
        if (ACCUM) v += F16OUT ? (float)((const f16*)Cp)[ci] : ((const float*)Cp)[ci];
        if (RELU) v = fmaxf(v, 0.0f);
        if (F16OUT) ((f16*)Cp)[ci] = (f16)v;
        else        ((float*)Cp)[ci] = v;
      }
    }
  }
}

// ============ small helper kernels ============
__global__ void k_cvt4(const float* __restrict__ a, f16* __restrict__ da,
                       const float* __restrict__ b, f16* __restrict__ db,
                       const float* __restrict__ c, f16* __restrict__ dc,
                       const float* __restrict__ d, f16* __restrict__ dd) {
  int i = blockIdx.x * 256 + threadIdx.x;   // 819200 total
  if (i < 262144) da[i] = (f16)a[i];
  else if (i < 524288) db[i - 262144] = (f16)b[i - 262144];
  else if (i < 786432) dc[i - 524288] = (f16)c[i - 524288];
  else if (i < 819200) dd[i - 786432] = (f16)d[i - 786432];
}

__global__ void k_build_cv(const float* __restrict__ C2, const float* __restrict__ mul,
                           f16* __restrict__ cv) {
  int i = blockIdx.x * 256 + threadIdx.x;   // 512*512
  int r = i >> 9;
  cv[i] = (f16)(C2[i] / mul[r]);
}

__global__ void k_build_dvt(const float* __restrict__ Dt, const float* __restrict__ mul,
                            f16* __restrict__ dvt) {
  int i = blockIdx.x * 256 + threadIdx.x;   // 64*512
  int k = i >> 9, n = i & 511;
  dvt[i] = (f16)(Dt[n * 64 + k] / mul[n]);
}

__global__ void k_2im(const float* __restrict__ s, f16* __restrict__ d) {
  int i = blockIdx.x * 256 + threadIdx.x;
  int r = i >> 9, c = i & 511;
  d[i] = (f16)(((r == c) ? 2.0f : 0.0f) - s[i]);
}

__global__ void k_tr16(const f16* __restrict__ s, f16* __restrict__ d, int R, int C) {
  int i = blockIdx.x * 256 + threadIdx.x;
  if (i < R * C) { int j = i / R, r = i % R; d[i] = s[r * C + j]; }
}

__global__ void k_woutt(const float* __restrict__ C1, const float* __restrict__ D11,
                        const float* __restrict__ D12, f16* __restrict__ Wo) {
  int i = blockIdx.x * 256 + threadIdx.x;   // 1088*64
  int k = i >> 6, j = i & 63;
  float v = (k < 512) ? C1[j * 512 + k]
          : (k < 1024) ? D11[j * 512 + (k - 512)]
                       : D12[j * 64 + (k - 1024)];
  Wo[i] = (f16)v;
}

__global__ void k_cb(const f16* __restrict__ X, const float* __restrict__ Fb,
                     float* __restrict__ cb) {
  int i = threadIdx.x;
  float a = 0.0f;
  for (int k = 0; k < 512; ++k) a += (float)X[i * 512 + k] * Fb[k];
  cb[i] = a;
}

__global__ void k_bias0(const f16* __restrict__ Cv, const float* __restrict__ cb,
                        const float* __restrict__ bv, float* __restrict__ b0) {
  int i = blockIdx.x * 512 + threadIdx.x;
  if (i < 512) b0[i] = cb[i];
  else {
    int j = i - 512;
    float a = bv[j];
    for (int k = 0; k < 512; ++k) a += (float)Cv[j * 512 + k] * cb[k];
    b0[i] = a;
  }
}

// u (B,NU,T) f32 -> UP2 [b][1025][64] f16 (row 1024 per batch = zero pad)
__global__ void k_packu(const float* __restrict__ u, f16* __restrict__ up) {
  __shared__ f16 tile[64][65];
  int b = blockIdx.y, t0 = blockIdx.x << 6;
  int tid = threadIdx.x;
  #pragma unroll
  for (int it = 0; it < 16; ++it) {
    int idx = it * 256 + tid; int i = idx >> 6, tt = idx & 63;
    tile[tt][i] = (f16)u[((long)b * 64 + i) * 1024 + t0 + tt];
  }
  __syncthreads();
  #pragma unroll
  for (int it = 0; it < 16; ++it) {
    int idx = it * 256 + tid; int tt = idx >> 6, i = idx & 63;
    up[((long)b * 1025 + t0 + tt) * 64 + i] = tile[tt][i];
  }
}

// Pack Wbig = [[A1 A2],[M1 M2]] (1024x1024 f16) into per-thread register layout.
__global__ void k_packw(const f16* __restrict__ A1, const f16* __restrict__ A2,
                        const f16* __restrict__ M1, const f16* __restrict__ M2,
                        unsigned int* __restrict__ Wp) {
  int U = blockIdx.x * 256 + threadIdx.x;   // 524288
  int p = U & 3; int V = U >> 2;
  int tid = V & 511; int sj = V >> 9;
  int jj = sj & 31; int s = sj >> 5;
  int q = tid & 3, r = tid >> 2;
  int R = s * 128 + r;
  int k = q * 256 + jj * 8 + p * 2;
  f16 g0, g1;
  if (R < 512) {
    if (k < 512) { g0 = A1[R * 512 + k];         g1 = A1[R * 512 + k + 1]; }
    else         { g0 = A2[R * 512 + k - 512];   g1 = A2[R * 512 + k - 511]; }
  } else {
    int Rm = R - 512;
    if (k < 512) { g0 = M1[Rm * 512 + k];        g1 = M1[Rm * 512 + k + 1]; }
    else         { g0 = M2[Rm * 512 + k - 512];  g1 = M2[Rm * 512 + k - 511]; }
  }
  unsigned int lo = __builtin_bit_cast(unsigned short, g0);
  unsigned int hi = __builtin_bit_cast(unsigned short, g1);
  Wp[U] = lo | (hi << 16);
}

// ring slot 0 (tag=0, h=0 | w0) + hist[0]
__global__ void k_tag0(const f16* __restrict__ W0, unsigned long long* __restrict__ ring,
                       unsigned int* __restrict__ hist) {
  int i = blockIdx.x * 256 + threadIdx.x;   // 32*512
  int b = i >> 9, j = i & 511;
  unsigned int pk = 0;
  if (j >= 256) pk = ((const unsigned int*)W0)[b * 256 + (j - 256)];
  ring[(long)b * 512 + j] = ((unsigned long long)pk << 32);   // {pk, tag=0}
  hist[(long)b * 512 + j] = pk;
}

// ============ the sequential scan: persistent, 256 WGs = 32 batches x 8 slices ============
// Ring entry (8B, atomic): {pk:hi32, tag:lo32}. Producer's data store IS the signal.
// Consumer wave w needs entries [64w,64w+64) (= slice w's output). Poll: all 64 lanes
// spin on ONE canary entry (broadcast, 1 transaction/round, s_sleep backoff) -> then
// per-lane load own entry + tag re-check (stragglers re-loop briefly). No flags, no
// fences, no producer drain. Ring depth 4: WG at t implies peers consumed t-2 (lockstep
// chain) => slot (t-4)&3 is free. hist written per-slice (256B) off the critical path.
__global__ __launch_bounds__(512, 1) void k_scan(
    const uint4* __restrict__ Wp4,
    const f16* __restrict__ bHV,
    const float* __restrict__ b0,
    unsigned long long* __restrict__ ring,  // [4][32][512]
    unsigned int* __restrict__ hist)        // [1024][32][512] packed f16 pairs
{
  const int wg = blockIdx.x;
  const int s = wg >> 5, b = wg & 31;
  const int tid = threadIdx.x;
  const int q = tid & 3, r = tid >> 2;     // 4-way K-split, 128 rows/slice
  const int R = (s << 7) + r;
  __shared__ __align__(16) unsigned int lds[2 * 528];   // double-buffered 132-padded chunks

  // weights: 128 dwords/thread, register-resident; asm keep-alive pins them (round-3
  // lesson: without it the compiler sinks the loads into the t-loop => 256KB/WG/step re-read)
  uint4 wreg[32];
  #pragma unroll
  for (int j = 0; j < 32; ++j) wreg[j] = Wp4[(long)(s * 32 + j) * 512 + tid];
  #pragma unroll
  for (int j = 0; j < 32; ++j)
    asm volatile("" : "+v"(wreg[j].x), "+v"(wreg[j].y), "+v"(wreg[j].z), "+v"(wreg[j].w));

  const float b0r = b0[R];
  const bool isV = (s >= 4);

  // bias pipeline: value for step t loaded during step t-1 (HBM latency off the path)
  float bsv = (float)bHV[((long)b * 1025 + 0) * 1024 + R];

  for (int t = 1; t < 1024; ++t) {
    float bsv_nx = (float)bHV[((long)b * 1025 + t) * 1024 + R];   // for t+1

    const unsigned long long* rb = ring + (((t - 1) & 3) * 32 + b) * 512;
    const int wb = tid & ~63;                 // wave's 64-entry block
    const unsigned int tg = (unsigned int)(t - 1);

    // canary poll: one broadcast 8B load per round
    for (;;) {
      unsigned long long c = __hip_atomic_load(rb + wb + 63, __ATOMIC_RELAXED,
                                               __HIP_MEMORY_SCOPE_AGENT);
      if ((unsigned int)c == tg) break;
      __builtin_amdgcn_s_sleep(1);
    }
    // per-lane verify load (usually valid immediately; stragglers re-loop)
    unsigned long long e = __hip_atomic_load(rb + tid, __ATOMIC_RELAXED,
                                             __HIP_MEMORY_SCOPE_AGENT);
    while ((unsigned int)e != tg)
      e = __hip_atomic_load(rb + tid, __ATOMIC_RELAXED, __HIP_MEMORY_SCOPE_AGENT);
    asm volatile("" ::: "memory");

    unsigned int pk = (unsigned int)(e >> 32);    // packed f16 pair (state dword tid)
    lds[(t & 1) * 528 + (tid >> 7) * 132 + (tid & 127)] = pk;
    __syncthreads();   // only barrier per step; prior-step stores long drained

    const unsigned int* lp = lds + (t & 1) * 528 + q * 132;
    float acc = 0.0f;
    #pragma unroll
    for (int jj = 0; jj < 32; ++jj) {
      uint4 s4 = *(const uint4*)(lp + jj * 4);
      acc = fdot2u(s4.x, wreg[jj].x, acc);
      acc = fdot2u(s4.y, wreg[jj].y, acc);
      acc = fdot2u(s4.z, wreg[jj].z, acc);
      acc = fdot2u(s4.w, wreg[jj].w, acc);
    }
    acc += __shfl_xor(acc, 1, 64);
    acc += __shfl_xor(acc, 2, 64);

    float val = acc + bsv + b0r;
    if (isV) val = fmaxf(val, 0.0f);
    f16 hv = (f16)val;
    unsigned int hb = (unsigned int)__builtin_bit_cast(unsigned short, hv);
    unsigned int nb = __shfl_down(hb, 4, 64);     // row r+1's value

    if ((tid & 7) == 0) {
      unsigned int pko = hb | (nb << 16);
      if (t < 1023)
        __hip_atomic_store(ring + ((t & 3) * 32 + b) * 512 + (R >> 1),
                           ((unsigned long long)pko << 32) | (unsigned long long)(unsigned int)t,
                           __ATOMIC_RELAXED, __HIP_MEMORY_SCOPE_AGENT);
      hist[((long)t * 32 + b) * 512 + (R >> 1)] = pko;   // off critical path, balanced
    }
    bsv = bsv_nx;
  }
}

// C32 [b][t][j] f32 -> out [b][j][t]
__global__ void k_trout(const float* __restrict__ C, float* __restrict__ out) {
  __shared__ float tile[64][65];
  int b = blockIdx.y, t0 = blockIdx.x << 6;
  int tid = threadIdx.x;
  #pragma unroll
  for (int it = 0; it < 16; ++it) {
    int idx = it * 256 + tid; int tt = idx >> 6, j = idx & 63;
    tile[j][tt] = C[((long)b * 1024 + t0 + tt) * 64 + j];
  }
  __syncthreads();
  #pragma unroll
  for (int it = 0; it < 16; ++it) {
    int idx = it * 256 + tid; int j = idx >> 6, tt = idx & 63;
    out[((long)b * 64 + j) * 1024 + t0 + tt] = tile[j][tt];
  }
}

// ============ host ============
extern "C" void kernel_launch(void* const* d_in, const int* in_sizes, int n_in,
                              void* d_out, int out_size, void* d_ws, size_t ws_size,
                              hipStream_t stream) {
  (void)in_sizes; (void)n_in; (void)out_size; (void)ws_size;
  const float* u   = (const float*)d_in[0];
  const float* E   = (const float*)d_in[1];
  const float* Fw  = (const float*)d_in[2];
  const float* Fb  = (const float*)d_in[3];
  const float* B1w = (const float*)d_in[4];
  const float* B2w = (const float*)d_in[5];
  const float* C2t = (const float*)d_in[6];
  const float* bv  = (const float*)d_in[7];
  const float* Dt  = (const float*)d_in[8];
  const float* C1w = (const float*)d_in[9];
  const float* D11 = (const float*)d_in[10];
  const float* D12 = (const float*)d_in[11];
  const float* by  = (const float*)d_in[12];
  const float* mul = (const float*)d_in[13];
  float* out = (float*)d_out;

  char* w = (char*)d_ws;
  size_t off = 0;
  auto alloc = [&](size_t bytes) { size_t o = off; off += (bytes + 255) & ~(size_t)255; return o; };

  f16*  UP2   = (f16*)(w + alloc(32L * 1025 * 64 * 2));  // u packed [b][1025][64], last row 0
  f16*  E16   = (f16*)(w + alloc(262144L * 2));
  f16*  F16   = (f16*)(w + alloc(262144L * 2));
  f16*  B116  = (f16*)(w + alloc(262144L * 2));
  f16*  B216  = (f16*)(w + alloc(32768L * 2));
  f16*  CV16  = (f16*)(w + alloc(262144L * 2));
  f16*  CATB  = (f16*)(w + alloc(65536L * 2));           // [CvA3T (64x512); DvT (64x512)]
  f16*  CVA3T = CATB;
  f16*  DVT   = CATB + 32768;
  f16*  XA    = (f16*)(w + alloc(262144L * 2));
  f16*  XB    = (f16*)(w + alloc(262144L * 2));
  f16*  Z16   = (f16*)(w + alloc(262144L * 2));
  float* Y32  = (float*)(w + alloc(262144L * 4));
  f16*  A1    = (f16*)(w + alloc(262144L * 2));
  f16*  A2    = (f16*)(w + alloc(262144L * 2));
  f16*  A3    = (f16*)(w + alloc(32768L * 2));
  f16*  M1    = (f16*)(w + alloc(262144L * 2));
  f16*  M2    = (f16*)(w + alloc(262144L * 2));
  f16*  CVA3  = (f16*)(w + alloc(32768L * 2));
  f16*  A3T   = (f16*)(w + alloc(32768L * 2));
  unsigned int* WPK = (unsigned int*)(w + alloc(524288L * 4));
  f16*  WOUT  = (f16*)(w + alloc(69632L * 2));           // 1088x64
  float* CB   = (float*)(w + alloc(512L * 4));
  float* B0   = (float*)(w + alloc(1024L * 4));
  f16*  W0    = (f16*)(w + alloc(16384L * 2));           // w0 (32x512)
  unsigned long long* RING = (unsigned long long*)(w + alloc(4L * 32 * 512 * 8)); // tagged ring
  f16*  BHV   = (f16*)(w + alloc(32L * 1025 * 1024 * 2));  // per-step biases [b][1025][1024]
  unsigned int* HIST = (unsigned int*)(w + alloc(1024L * 32 * 512 * 4)); // state history
  float* C32  = (float*)(w + alloc(2097152L * 4));         // y pre-transpose [b][t][64]

  // init (ws re-poisoned to 0xAA before every timed launch; tag 0xAAAAAAAA never matches)
  (void)hipMemsetAsync(UP2, 0, 32L * 1025 * 64 * 2, stream);   // zero pad rows

  k_packu<<<dim3(16, 32), 256, 0, stream>>>(u, UP2);
  k_cvt4<<<3200, 256, 0, stream>>>(E, E16, Fw, F16, B1w, B116, B2w, B216);
  k_build_cv<<<1024, 256, 0, stream>>>(C2t, mul, CV16);
  k_build_dvt<<<128, 256, 0, stream>>>(Dt, mul, DVT);

  // Newton: X <- X(2I - E X), X0 = 2I - E (3 iters: residual ~2.6e-6 << f16 floor)
  k_2im<<<1024, 256, 0, stream>>>(E, XA);
  f16 *X = XA, *Xo = XB;
  for (int it = 0; it < 3; ++it) {
    gemm16<0,0,0,0><<<dim3(8,8,1), 256, 0, stream>>>(E16, 512, 0, X, 512, Y32, 512, 0, nullptr, 512, 512, 512);
    k_2im<<<1024, 256, 0, stream>>>(Y32, Z16);
    gemm16<1,0,0,0><<<dim3(8,8,1), 256, 0, stream>>>(X, 512, 0, Z16, 512, Xo, 512, 0, nullptr, 512, 512, 512);
    f16* tmp = X; X = Xo; Xo = tmp;
  }

  // fused weights
  gemm16<1,0,0,0><<<dim3(8,8,1), 256, 0, stream>>>(X, 512, 0, F16, 512, A1, 512, 0, nullptr, 512, 512, 512);
  gemm16<1,0,0,0><<<dim3(8,8,1), 256, 0, stream>>>(X, 512, 0, B116, 512, A2, 512, 0, nullptr, 512, 512, 512);
  gemm16<1,0,0,0><<<dim3(8,1,1), 256, 0, stream>>>(X, 512, 0, B216, 64, A3, 64, 0, nullptr, 512, 64, 512);
  gemm16<1,0,0,0><<<dim3(8,8,1), 256, 0, stream>>>(CV16, 512, 0, A1, 512, M1, 512, 0, nullptr, 512, 512, 512);
  gemm16<1,0,0,0><<<dim3(8,8,1), 256, 0, stream>>>(CV16, 512, 0, A2, 512, M2, 512, 0, nullptr, 512, 512, 512);
  gemm16<1,0,0,0><<<dim3(8,1,1), 256, 0, stream>>>(CV16, 512, 0, A3, 64, CVA3, 64, 0, nullptr, 512, 64, 512);
  k_tr16<<<128, 256, 0, stream>>>(A3, A3T, 512, 64);
  k_tr16<<<128, 256, 0, stream>>>(CVA3, CVA3T, 512, 64);
  k_woutt<<<272, 256, 0, stream>>>(C1w, D11, D12, WOUT);
  k_cb<<<1, 512, 0, stream>>>(X, Fb, CB);
  k_bias0<<<2, 512, 0, stream>>>(CV16, CB, bv, B0);
  k_packw<<<2048, 256, 0, stream>>>(A1, A2, M1, M2, WPK);

  // per-step input biases into BHV [b][1025][1024]:
  //   biasH[t] = u_t @ A3T ; biasV[t] = [u_t ; u_{t+1}] @ [CvA3T ; DvT] (K=128, fused)
  gemm16<1,0,0,0><<<dim3(513,8,1), 256, 0, stream>>>(UP2, 64, 0, A3T, 512, BHV, 1024, 0, nullptr, 32800, 512, 64);
  gemm16<1,0,0,0><<<dim3(513,8,1), 256, 0, stream>>>(UP2, 64, 0, CVA3T, 512, BHV + 512, 1024, 0, nullptr, 32800, 512, 128);
  // w0 = relu(u_0 @ DvT + bv) -> W0, then seed ring slot 0 + hist[0]
  gemm16<1,0,1,1><<<dim3(1,8,32), 256, 0, stream>>>(UP2, 64, 65600, DVT, 512, W0, 512, 512, bv, 1, 512, 64);
  k_tag0<<<64, 256, 0, stream>>>(W0, RING, HIST);

  // the sequential recurrence
  k_scan<<<256, 512, 0, stream>>>((const uint4*)WPK, BHV, B0, RING, HIST);

  // y = [h;w] @ WoutT[0:1024] + u @ WoutT[1024:1088] + by   (batched over b)
  gemm16<0,0,0,0><<<dim3(16,1,32), 256, 0, stream>>>((const f16*)HIST, 32768, 1024, WOUT, 64, C32, 64, 65536, nullptr, 1024, 64, 1024);
  gemm16<0,1,0,1><<<dim3(16,1,32), 256, 0, stream>>>(UP2, 64, 65600, WOUT + 65536, 64, C32, 64, 65536, by, 1024, 64, 64);
  k_trout<<<dim3(16, 32), 256, 0, stream>>>(C32, out);
}